// Round 5
// baseline (29.780 us; speedup 1.0000x reference)
//
#include <hip/hip_runtime.h>

// Problem constants (from reference)
constexpr int N = 2;
constexpr int C = 20;
constexpr int H = 64;
constexpr int W = 2048;          // power of two -> wrap via & (W-1)
constexpr int HW = H * W;

constexpr int BLK  = 256;
constexpr int OPT  = 2;              // outputs per thread (even col pair)
constexpr int TILE = BLK * OPT;      // 512 cols per block
// grid = N*H*(W/TILE) = 2*64*4 = 512 blocks

__global__ __launch_bounds__(BLK, 2)
void lcl_xyz_kernel(const float* __restrict__ xyz,
                    const float* __restrict__ softmax,
                    const int* __restrict__ mask,
                    float* __restrict__ out) {
    const int t = threadIdx.x;

    // XCD-contiguous h-strip swizzle: XCD (bid%8) owns work ids [xcd*64, xcd*64+64)
    // -> 16 contiguous (n*64+h) rows per XCD -> halo rows shared within one L2.
    const int bid  = blockIdx.x;
    const int work = (bid & 7) * 64 + (bid >> 3);   // bijective, [0,512)
    const int nh   = work >> 2;                     // n*64+h in [0,128)
    const int bw   = work & 3;
    const int n    = nh >> 6;
    const int h    = nh & 63;
    const int w    = bw * TILE + 2 * t;             // even; first output col

    // Clipped row offsets + validity (compile-time indexed everywhere)
    int  rowoff[5];
    bool hv[5];
    #pragma unroll
    for (int r = 0; r < 5; ++r) {
        int hh = h - 2 + r;
        hv[r] = (unsigned)hh < (unsigned)H;
        rowoff[r] = min(max(hh, 0), H - 1) * W;
    }

    // Aligned float2 column offsets covering cols w-2 .. w+3
    const int cm = (w - 2) & (W - 1);
    const int c0 = w;
    const int cp = (w + 2) & (W - 1);

    const float* xb = xyz + (size_t)(n * 3 + 0) * HW;
    const float* yb = xyz + (size_t)(n * 3 + 1) * HW;
    const float* zb = xyz + (size_t)(n * 3 + 2) * HW;
    const int*   mb = mask + (size_t)n * HW;

    // Centers at (h, w) and (h, w+1)
    const float2 cx2 = *(const float2*)(xb + h * W + c0);
    const float2 cy2 = *(const float2*)(yb + h * W + c0);
    const float2 cz2 = *(const float2*)(zb + h * W + c0);

    // ---- Weight phase: 50 gaussian*mask*valid weights in registers ----
    float wa[5][5], wb_[5][5];
    #pragma unroll
    for (int r = 0; r < 5; ++r) {
        float2 xm = *(const float2*)(xb + rowoff[r] + cm);
        float2 x0 = *(const float2*)(xb + rowoff[r] + c0);
        float2 xp = *(const float2*)(xb + rowoff[r] + cp);
        float2 ym = *(const float2*)(yb + rowoff[r] + cm);
        float2 y0 = *(const float2*)(yb + rowoff[r] + c0);
        float2 yp = *(const float2*)(yb + rowoff[r] + cp);
        float2 zm = *(const float2*)(zb + rowoff[r] + cm);
        float2 z0 = *(const float2*)(zb + rowoff[r] + c0);
        float2 zp = *(const float2*)(zb + rowoff[r] + cp);
        int2   km = *(const int2*)(mb + rowoff[r] + cm);
        int2   k0 = *(const int2*)(mb + rowoff[r] + c0);
        int2   kp = *(const int2*)(mb + rowoff[r] + cp);

        const float xv[6] = {xm.x, xm.y, x0.x, x0.y, xp.x, xp.y};
        const float yv[6] = {ym.x, ym.y, y0.x, y0.y, yp.x, yp.y};
        const float zv[6] = {zm.x, zm.y, z0.x, z0.y, zp.x, zp.y};
        const int   mv[6] = {km.x, km.y, k0.x, k0.y, kp.x, kp.y};

        #pragma unroll
        for (int j = 0; j < 5; ++j) {
            {
                float dx = xv[j] - cx2.x, dy = yv[j] - cy2.x, dz = zv[j] - cz2.x;
                float g  = __expf(-0.5f * (dx * dx + dy * dy + dz * dz));
                wa[r][j] = (hv[r] && mv[j]) ? g : 0.0f;
            }
            {
                float dx = xv[j + 1] - cx2.y, dy = yv[j + 1] - cy2.y, dz = zv[j + 1] - cz2.y;
                float g  = __expf(-0.5f * (dx * dx + dy * dy + dz * dz));
                wb_[r][j] = (hv[r] && mv[j + 1]) ? g : 0.0f;
            }
        }
    }

    // ---- Class loop: register-double-buffered, no LDS, no barriers ----
    const float* smb = softmax + (size_t)n * C * HW;
    float*       ob  = out + (size_t)n * C * HW + (size_t)h * W + w;

    float2 A0[5], A1[5], A2[5];      // buffer A: 5 rows x 3 float2
    float2 B0[5], B1[5], B2[5];      // buffer B

#define LOADS(b0, b1, b2, c)                                              \
    do {                                                                  \
        const float* sc = smb + (size_t)(c) * HW;                         \
        _Pragma("unroll")                                                 \
        for (int r = 0; r < 5; ++r) {                                     \
            b0[r] = *(const float2*)(sc + rowoff[r] + cm);                \
            b1[r] = *(const float2*)(sc + rowoff[r] + c0);                \
            b2[r] = *(const float2*)(sc + rowoff[r] + cp);                \
        }                                                                 \
    } while (0)

#define COMP(b0, b1, b2, c)                                               \
    do {                                                                  \
        float a0 = 0.0f, a1 = 0.0f;                                       \
        _Pragma("unroll")                                                 \
        for (int r = 0; r < 5; ++r) {                                     \
            float v0 = b0[r].x, v1 = b0[r].y;                             \
            float v2 = b1[r].x, v3 = b1[r].y;                             \
            float v4 = b2[r].x, v5 = b2[r].y;                             \
            a0 = fmaf(wa[r][0], v0, a0);                                  \
            a0 = fmaf(wa[r][1], v1, a0);                                  \
            a0 = fmaf(wa[r][2], v2, a0);                                  \
            a0 = fmaf(wa[r][3], v3, a0);                                  \
            a0 = fmaf(wa[r][4], v4, a0);                                  \
            a1 = fmaf(wb_[r][0], v1, a1);                                 \
            a1 = fmaf(wb_[r][1], v2, a1);                                 \
            a1 = fmaf(wb_[r][2], v3, a1);                                 \
            a1 = fmaf(wb_[r][3], v4, a1);                                 \
            a1 = fmaf(wb_[r][4], v5, a1);                                 \
        }                                                                 \
        float2 o; o.x = a0; o.y = a1;                                     \
        *(float2*)(ob + (size_t)(c) * HW) = o;                            \
    } while (0)

    LOADS(A0, A1, A2, 0);
    #pragma unroll
    for (int c = 0; c < C; c += 2) {
        LOADS(B0, B1, B2, c + 1);            // prefetch c+1 while computing c
        COMP(A0, A1, A2, c);
        if (c + 2 < C) LOADS(A0, A1, A2, c + 2);   // prefetch c+2 during c+1
        COMP(B0, B1, B2, c + 1);
    }
#undef LOADS
#undef COMP
}

extern "C" void kernel_launch(void* const* d_in, const int* in_sizes, int n_in,
                              void* d_out, int out_size, void* d_ws, size_t ws_size,
                              hipStream_t stream) {
    const float* xyz     = (const float*)d_in[0];
    const float* softmax = (const float*)d_in[1];
    const int*   mask    = (const int*)d_in[2];
    float*       out     = (float*)d_out;

    const int grid = N * H * (W / TILE);     // 512 blocks
    lcl_xyz_kernel<<<grid, BLK, 0, stream>>>(xyz, softmax, mask, out);
}